// Round 1
// baseline (1269.832 us; speedup 1.0000x reference)
//
#include <hip/hip_runtime.h>
#include <math.h>

// Problem constants (S4Checkpointed): b=2, L=2048, d=768, n=16, r=48
#define BATCH 2
#define LSEQ  2048
#define DIM   768
#define NST   16
#define RDT   48
#define BL    (BATCH*LSEQ)   // 4096

// -------- Kernel A: sliced projection --------------------------------------
// Only rows 0..15 (B), 32..47 (C), 1584..1631 (dt) of W_xproj are used.
// Block = 256 threads (4 waves), handles 16 (b,l) rows. x rows staged in LDS.
// Each wave computes 20 of the 80 output rows: W row in 12 registers/lane,
// 64-lane shuffle reduce per (j,l) dot.
__global__ __launch_bounds__(256) void proj_kernel(
        const float* __restrict__ x, const float* __restrict__ Wx,
        float* __restrict__ Bc, float* __restrict__ Cc, float* __restrict__ dtp) {
    __shared__ float xs[16 * DIM];   // 48 KB
    const int bl0 = blockIdx.x * 16;
    const int tid = threadIdx.x;
    const float* xsrc = x + (size_t)bl0 * DIM;
    for (int i = tid; i < 16 * DIM; i += 256) xs[i] = xsrc[i];
    __syncthreads();

    const int wave = tid >> 6;
    const int lane = tid & 63;
    for (int jj = 0; jj < 20; ++jj) {
        const int j = wave * 20 + jj;                  // 0..79
        // j<16 -> W row j (B); 16<=j<32 -> row 32+(j-16) (C); j>=32 -> row 1584+(j-32) (dt)
        const int row = (j < 16) ? j : ((j < 32) ? (j + 16) : (j + 1552));
        const float* wrow = Wx + (size_t)row * DIM;
        float w[12];
        #pragma unroll
        for (int i = 0; i < 12; ++i) w[i] = wrow[lane + i * 64];
        for (int l = 0; l < 16; ++l) {
            float s = 0.f;
            #pragma unroll
            for (int i = 0; i < 12; ++i) s += w[i] * xs[l * DIM + lane + i * 64];
            #pragma unroll
            for (int m = 32; m >= 1; m >>= 1) s += __shfl_xor(s, m, 64);
            if (lane == 0) {
                const int bl = bl0 + l;
                if (j < 16)       Bc[bl * NST + j]        = s;
                else if (j < 32)  Cc[bl * NST + (j - 16)] = s;
                else              dtp[bl * RDT + (j - 32)] = s;
            }
        }
    }
}

// -------- Kernel B: delta = softplus(dtp @ W_dt.T + 2*b_dt) ----------------
// Grid: 3 d-tiles x 256 bl-tiles. Thread owns one d; W_dt row in 12 float4
// registers; dtp rows broadcast from LDS; coalesced delta write (b,l,d).
__global__ __launch_bounds__(256) void delta_kernel(
        const float* __restrict__ dtp, const float* __restrict__ Wdt,
        const float* __restrict__ bdt, float* __restrict__ delta) {
    __shared__ float dts[16 * RDT];
    const int dtile = blockIdx.x % 3;
    const int bl0 = (blockIdx.x / 3) * 16;
    const int tid = threadIdx.x;
    const int d = dtile * 256 + tid;

    for (int i = tid; i < 16 * RDT; i += 256) dts[i] = dtp[(size_t)bl0 * RDT + i];
    __syncthreads();

    float4 w[12];
    const float4* wr = (const float4*)(Wdt + (size_t)d * RDT);  // 192B/row, 16B aligned
    #pragma unroll
    for (int i = 0; i < 12; ++i) w[i] = wr[i];
    const float bb = 2.0f * bdt[d];

    for (int l = 0; l < 16; ++l) {
        float acc = bb;
        const float4* t4 = (const float4*)(dts + l * RDT);
        #pragma unroll
        for (int i = 0; i < 12; ++i) {
            const float4 tv = t4[i];
            acc += w[i].x * tv.x + w[i].y * tv.y + w[i].z * tv.z + w[i].w * tv.w;
        }
        const float sp = (acc > 20.f) ? acc : log1pf(__expf(acc));
        delta[(size_t)(bl0 + l) * DIM + d] = sp;
    }
}

// -------- Kernel C: selective scan + epilogue ------------------------------
// 16 lanes per (b,d) channel (lane = state index n). h in a register.
// Per t: dA=exp(delta*A); h=dA*h+delta*x*B; y=sum_n h*C (4 shuffle-adds);
// out = (y + x*D) * silu(z^T). 96 blocks x 256 threads = 1536 channels.
__global__ __launch_bounds__(256) void scan_kernel(
        const float* __restrict__ x, const float* __restrict__ z,
        const float* __restrict__ A_log, const float* __restrict__ Dp,
        const float* __restrict__ Bc, const float* __restrict__ Cc,
        const float* __restrict__ delta, float* __restrict__ out) {
    const int tid = threadIdx.x;
    const int c  = tid >> 4;         // channel within block
    const int nn = tid & 15;         // state index
    const int ch = blockIdx.x * 16 + c;
    const int b = ch / DIM;
    const int d = ch % DIM;

    const float Aln = -__expf(A_log[d * NST + nn]);   // A = -exp(A_log)
    const float Dd = Dp[d];
    const float* dl_p = delta + (size_t)b * LSEQ * DIM + d;
    const float* x_p  = x     + (size_t)b * LSEQ * DIM + d;
    const float* B_p  = Bc + (size_t)b * LSEQ * NST + nn;
    const float* C_p  = Cc + (size_t)b * LSEQ * NST + nn;
    const float* z_p  = z + ((size_t)b * DIM + d) * LSEQ;
    float* o_p = out + (size_t)b * LSEQ * DIM + d;

    float h = 0.f;
    #pragma unroll 4
    for (int t = 0; t < LSEQ; ++t) {
        const float dl = dl_p[(size_t)t * DIM];
        const float xv = x_p[(size_t)t * DIM];
        const float Bv = B_p[t * NST];
        const float Cv = C_p[t * NST];
        const float dA = __expf(dl * Aln);
        h = fmaf(dA, h, dl * xv * Bv);
        float p = h * Cv;
        p += __shfl_xor(p, 1, 64);
        p += __shfl_xor(p, 2, 64);
        p += __shfl_xor(p, 4, 64);
        p += __shfl_xor(p, 8, 64);
        if (nn == 0) {
            const float zv = z_p[t];
            const float y = fmaf(xv, Dd, p);
            const float sig = 1.0f / (1.0f + __expf(-zv));
            o_p[(size_t)t * DIM] = y * zv * sig;
        }
    }
}

extern "C" void kernel_launch(void* const* d_in, const int* in_sizes, int n_in,
                              void* d_out, int out_size, void* d_ws, size_t ws_size,
                              hipStream_t stream) {
    const float* x     = (const float*)d_in[0];  // (2,2048,768)
    const float* z     = (const float*)d_in[1];  // (2,768,2048)
    const float* A_log = (const float*)d_in[2];  // (768,16)
    const float* D     = (const float*)d_in[3];  // (768,)
    const float* Wx    = (const float*)d_in[4];  // (1680,768)
    const float* Wdt   = (const float*)d_in[5];  // (768,48)
    const float* bdt   = (const float*)d_in[6];  // (768,)
    float* out = (float*)d_out;

    // workspace layout (floats): Bc[4096*16] | Cc[4096*16] | dtp[4096*48] | delta[4096*768]
    float* ws    = (float*)d_ws;
    float* Bc    = ws;
    float* Cc    = ws + (size_t)BL * NST;
    float* dtp   = ws + (size_t)2 * BL * NST;
    float* delta = ws + (size_t)2 * BL * NST + (size_t)BL * RDT;

    hipLaunchKernelGGL(proj_kernel,  dim3(BL / 16),        dim3(256), 0, stream, x, Wx, Bc, Cc, dtp);
    hipLaunchKernelGGL(delta_kernel, dim3(3 * (BL / 16)),  dim3(256), 0, stream, dtp, Wdt, bdt, delta);
    hipLaunchKernelGGL(scan_kernel,  dim3(BATCH * DIM / 16), dim3(256), 0, stream, x, z, A_log, D, Bc, Cc, delta, out);
}

// Round 2
// 384.114 us; speedup vs baseline: 3.3059x; 3.3059x over previous
//
#include <hip/hip_runtime.h>
#include <math.h>

// Problem constants (S4Checkpointed): b=2, L=2048, d=768, n=16, r=48
#define BATCH 2
#define LSEQ  2048
#define DIM   768
#define NST   16
#define RDT   48
#define BL    (BATCH*LSEQ)   // 4096
#define NCHUNK 16
#define CLEN   (LSEQ/NCHUNK) // 128

// -------- Kernel A: sliced projection --------------------------------------
// Only rows 0..15 (B), 32..47 (C), 1584..1631 (dt) of W_xproj are used.
// B/C written TRANSPOSED as (b, n, L) so the scan can float4-load along t.
__global__ __launch_bounds__(256) void proj_kernel(
        const float* __restrict__ x, const float* __restrict__ Wx,
        float* __restrict__ BcT, float* __restrict__ CcT, float* __restrict__ dtp) {
    __shared__ float xs[16 * DIM];   // 48 KB
    const int bl0 = blockIdx.x * 16;
    const int tid = threadIdx.x;
    const float* xsrc = x + (size_t)bl0 * DIM;
    for (int i = tid; i < 16 * DIM / 4; i += 256)
        ((float4*)xs)[i] = ((const float4*)xsrc)[i];
    __syncthreads();

    const int wave = tid >> 6;
    const int lane = tid & 63;
    for (int jj = 0; jj < 20; ++jj) {
        const int j = wave * 20 + jj;                  // 0..79
        const int row = (j < 16) ? j : ((j < 32) ? (j + 16) : (j + 1552));
        const float* wrow = Wx + (size_t)row * DIM;
        float w[12];
        #pragma unroll
        for (int i = 0; i < 12; ++i) w[i] = wrow[lane + i * 64];
        for (int l = 0; l < 16; ++l) {
            float s = 0.f;
            #pragma unroll
            for (int i = 0; i < 12; ++i) s += w[i] * xs[l * DIM + lane + i * 64];
            #pragma unroll
            for (int m = 32; m >= 1; m >>= 1) s += __shfl_xor(s, m, 64);
            if (lane == 0) {
                const int bl = bl0 + l;
                const int b = bl >> 11;       // /2048
                const int ll = bl & 2047;
                if (j < 16)       BcT[((size_t)(b * NST + j)) * LSEQ + ll]        = s;
                else if (j < 32)  CcT[((size_t)(b * NST + (j - 16))) * LSEQ + ll] = s;
                else              dtp[(size_t)bl * RDT + (j - 32)] = s;
            }
        }
    }
}

// -------- Kernel T: 64x64 tiled transpose (b,R,C) -> (b,C,R) ---------------
__global__ __launch_bounds__(256) void xpose_kernel(
        const float* __restrict__ in, float* __restrict__ out, int R, int C) {
    __shared__ float tile[64][65];
    const int r0 = blockIdx.x * 64;
    const int c0 = blockIdx.y * 64;
    const int b  = blockIdx.z;
    const int tx = threadIdx.x & 63;
    const int ty = threadIdx.x >> 6;
    #pragma unroll
    for (int k = 0; k < 16; ++k) {
        const int r = ty * 16 + k;
        tile[r][tx] = in[((size_t)b * R + (r0 + r)) * C + c0 + tx];
    }
    __syncthreads();
    #pragma unroll
    for (int k = 0; k < 16; ++k) {
        const int r = ty * 16 + k;
        out[((size_t)b * C + (c0 + r)) * R + r0 + tx] = tile[tx][r];
    }
}

// -------- Kernel B: deltaT = softplus(dtp @ W_dt.T + 2*b_dt), (b,d,l) ------
// Thread owns one (b,l); loops over 32 d's; writes coalesced along l.
__global__ __launch_bounds__(256) void delta_kernel(
        const float* __restrict__ dtp, const float* __restrict__ Wdt,
        const float* __restrict__ bdt, float* __restrict__ deltaT) {
    const int tid = threadIdx.x;
    const int bl = blockIdx.x * 256 + tid;
    const int b = bl >> 11;
    const int l = bl & 2047;
    const int d0 = blockIdx.y * 32;

    float4 t4[12];
    const float4* src = (const float4*)(dtp + (size_t)bl * RDT);
    #pragma unroll
    for (int i = 0; i < 12; ++i) t4[i] = src[i];

    for (int dd = 0; dd < 32; ++dd) {
        const int d = d0 + dd;
        const float4* wr = (const float4*)(Wdt + (size_t)d * RDT);
        float acc = 2.0f * bdt[d];
        #pragma unroll
        for (int i = 0; i < 12; ++i) {
            const float4 wv = wr[i];
            acc += wv.x * t4[i].x + wv.y * t4[i].y + wv.z * t4[i].z + wv.w * t4[i].w;
        }
        const float sp = (acc > 20.f) ? acc : log1pf(__expf(acc));
        deltaT[((size_t)b * DIM + d) * LSEQ + l] = sp;
    }
}

// -------- Kernel C: chunked 3-phase selective scan -------------------------
// One block per (b,d). 16 groups x 16 n-lanes; group g scans t in [g*128,(g+1)*128).
// Phase 1: local scan (h0=0) -> per-chunk (P,q). P = exp(Aln * sum(delta)).
// Phase 2: 16-step serial stitch over chunks (one group).
// Phase 3: re-scan with correct h0, reduce y over n, fuse +x*D.
// Epilogue: y *= silu(z) (z is natively (b,d,l)); write yT coalesced.
__global__ __launch_bounds__(256) void scan_kernel(
        const float* __restrict__ xT, const float* __restrict__ z,
        const float* __restrict__ A_log, const float* __restrict__ Dp,
        const float* __restrict__ BcT, const float* __restrict__ CcT,
        const float* __restrict__ deltaT, float* __restrict__ yT) {
    __shared__ float sdel[LSEQ];   // 8 KB; phase 3 re-uses it as the y buffer
    __shared__ float sx[LSEQ];     // 8 KB
    __shared__ float sP[NCHUNK][NST], sq[NCHUNK][NST], scar[NCHUNK][NST];

    const int tid = threadIdx.x;
    const int ch = blockIdx.x;           // b*768 + d
    const int b = ch / DIM;
    const int d = ch % DIM;
    const size_t row = (size_t)ch * LSEQ;

    // stage delta + x rows (coalesced float4)
    {
        const float4* s1 = (const float4*)(deltaT + row);
        const float4* s2 = (const float4*)(xT + row);
        float4* d1 = (float4*)sdel;
        float4* d2 = (float4*)sx;
        for (int i = tid; i < LSEQ / 4; i += 256) { d1[i] = s1[i]; d2[i] = s2[i]; }
    }
    __syncthreads();

    const int g = tid >> 4;
    const int n = tid & 15;
    const float Aln = -__expf(A_log[d * NST + n]);
    const int t0 = g * CLEN;
    const float* Bbase = BcT + ((size_t)(b * NST + n)) * LSEQ + t0;
    const float* Cbase = CcT + ((size_t)(b * NST + n)) * LSEQ + t0;

    // ---- phase 1: local scan, h0 = 0
    float h = 0.f, dsum = 0.f;
    for (int k = 0; k < CLEN; k += 4) {
        const float4 B4 = *(const float4*)(Bbase + k);
        #pragma unroll
        for (int j = 0; j < 4; ++j) {
            const int t = t0 + k + j;
            const float dl = sdel[t];
            const float xv = sx[t];
            const float Bv = (j == 0) ? B4.x : (j == 1) ? B4.y : (j == 2) ? B4.z : B4.w;
            dsum += dl;
            const float dA = __expf(dl * Aln);
            h = fmaf(dA, h, dl * xv * Bv);
        }
    }
    sP[g][n] = __expf(Aln * dsum);   // product of all dA over the chunk
    sq[g][n] = h;
    __syncthreads();

    // ---- phase 2: serial stitch over 16 chunks (one group)
    if (tid < NST) {
        float car = 0.f;
        #pragma unroll
        for (int c = 0; c < NCHUNK; ++c) {
            scar[c][tid] = car;
            car = fmaf(sP[c][tid], car, sq[c][tid]);
        }
    }
    __syncthreads();

    // ---- phase 3: re-scan with correct h0; y_t = sum_n C*h (+ x*D)
    const float Dd = Dp[d];
    h = scar[g][n];
    for (int k = 0; k < CLEN; k += 4) {
        const float4 B4 = *(const float4*)(Bbase + k);
        const float4 C4 = *(const float4*)(Cbase + k);
        #pragma unroll
        for (int j = 0; j < 4; ++j) {
            const int t = t0 + k + j;
            const float dl = sdel[t];
            const float xv = sx[t];
            const float Bv = (j == 0) ? B4.x : (j == 1) ? B4.y : (j == 2) ? B4.z : B4.w;
            const float Cv = (j == 0) ? C4.x : (j == 1) ? C4.y : (j == 2) ? C4.z : C4.w;
            const float dA = __expf(dl * Aln);
            h = fmaf(dA, h, dl * xv * Bv);
            float p = h * Cv;
            p += __shfl_xor(p, 1);
            p += __shfl_xor(p, 2);
            p += __shfl_xor(p, 4);
            p += __shfl_xor(p, 8);
            if (n == 0) sdel[t] = fmaf(xv, Dd, p);   // reuse sdel as y buffer
        }
    }
    __syncthreads();

    // ---- epilogue: y *= silu(z), write yT (coalesced)
    const float* zrow = z + row;
    float* yrow = yT + row;
    for (int i = tid; i < LSEQ; i += 256) {
        const float zv = zrow[i];
        const float sig = 1.0f / (1.0f + __expf(-zv));
        yrow[i] = sdel[i] * zv * sig;
    }
}

extern "C" void kernel_launch(void* const* d_in, const int* in_sizes, int n_in,
                              void* d_out, int out_size, void* d_ws, size_t ws_size,
                              hipStream_t stream) {
    const float* x     = (const float*)d_in[0];  // (2,2048,768)
    const float* z     = (const float*)d_in[1];  // (2,768,2048)
    const float* A_log = (const float*)d_in[2];  // (768,16)
    const float* D     = (const float*)d_in[3];  // (768,)
    const float* Wx    = (const float*)d_in[4];  // (1680,768)
    const float* Wdt   = (const float*)d_in[5];  // (768,48)
    const float* bdt   = (const float*)d_in[6];  // (768,)
    float* out = (float*)d_out;

    // ws layout (floats):
    //   BcT   [2*16*2048]   =  65536
    //   CcT   [2*16*2048]   =  65536
    //   dtp   [4096*48]     = 196608
    //   xT    [2*768*2048]  = 3145728
    //   deltaT[2*768*2048]  = 3145728   (scan writes yT over it)
    float* ws     = (float*)d_ws;
    float* BcT    = ws;
    float* CcT    = BcT + (size_t)BATCH * NST * LSEQ;
    float* dtp    = CcT + (size_t)BATCH * NST * LSEQ;
    float* xT     = dtp + (size_t)BL * RDT;
    float* deltaT = xT + (size_t)BATCH * DIM * LSEQ;
    float* yT     = deltaT;  // aliased: each block overwrites only its own staged row

    hipLaunchKernelGGL(proj_kernel, dim3(BL / 16), dim3(256), 0, stream,
                       x, Wx, BcT, CcT, dtp);
    hipLaunchKernelGGL(xpose_kernel, dim3(LSEQ / 64, DIM / 64, BATCH), dim3(256), 0, stream,
                       x, xT, LSEQ, DIM);
    hipLaunchKernelGGL(delta_kernel, dim3(BL / 256, DIM / 32), dim3(256), 0, stream,
                       dtp, Wdt, bdt, deltaT);
    hipLaunchKernelGGL(scan_kernel, dim3(BATCH * DIM), dim3(256), 0, stream,
                       xT, z, A_log, D, BcT, CcT, deltaT, yT);
    hipLaunchKernelGGL(xpose_kernel, dim3(DIM / 64, LSEQ / 64, BATCH), dim3(256), 0, stream,
                       yT, out, DIM, LSEQ);
}

// Round 3
// 317.513 us; speedup vs baseline: 3.9993x; 1.2098x over previous
//
#include <hip/hip_runtime.h>
#include <math.h>

// Problem constants (S4Checkpointed): b=2, L=2048, d=768, n=16, r=48
#define BATCH 2
#define LSEQ  2048
#define DIM   768
#define NST   16
#define RDT   48
#define BL    (BATCH*LSEQ)   // 4096
#define NCHUNK 16
#define CLEN   (LSEQ/NCHUNK) // 128
#define CPAD   132           // chunk stride in floats: 132%32==4 -> group g on banks 4g..4g+3
#define CPAD4  (CPAD/4)      // 33 float4s per chunk

// -------- Kernel A: sliced projection --------------------------------------
// Only rows 0..15 (B), 32..47 (C), 1584..1631 (dt) of W_xproj are used.
// B/C written transposed as (b, n, L); dt written transposed as (b, r, L)
// so the scan's fused delta phase loads coalesced along t.
__global__ __launch_bounds__(256) void proj_kernel(
        const float* __restrict__ x, const float* __restrict__ Wx,
        float* __restrict__ BcT, float* __restrict__ CcT, float* __restrict__ dtpT) {
    __shared__ float xs[16 * DIM];   // 48 KB
    const int bl0 = blockIdx.x * 16;
    const int tid = threadIdx.x;
    const float* xsrc = x + (size_t)bl0 * DIM;
    for (int i = tid; i < 16 * DIM / 4; i += 256)
        ((float4*)xs)[i] = ((const float4*)xsrc)[i];
    __syncthreads();

    const int wave = tid >> 6;
    const int lane = tid & 63;
    for (int jj = 0; jj < 20; ++jj) {
        const int j = wave * 20 + jj;                  // 0..79
        const int row = (j < 16) ? j : ((j < 32) ? (j + 16) : (j + 1552));
        const float* wrow = Wx + (size_t)row * DIM;
        float w[12];
        #pragma unroll
        for (int i = 0; i < 12; ++i) w[i] = wrow[lane + i * 64];
        for (int l = 0; l < 16; ++l) {
            float s = 0.f;
            #pragma unroll
            for (int i = 0; i < 12; ++i) s += w[i] * xs[l * DIM + lane + i * 64];
            #pragma unroll
            for (int m = 32; m >= 1; m >>= 1) s += __shfl_xor(s, m, 64);
            if (lane == 0) {
                const int bl = bl0 + l;
                const int b = bl >> 11;       // /2048
                const int ll = bl & 2047;
                if (j < 16)       BcT[((size_t)(b * NST + j)) * LSEQ + ll]         = s;
                else if (j < 32)  CcT[((size_t)(b * NST + (j - 16))) * LSEQ + ll]  = s;
                else              dtpT[((size_t)(b * RDT + (j - 32))) * LSEQ + ll] = s;
            }
        }
    }
}

// -------- Kernel T: 64x64 tiled transpose (b,R,C) -> (b,C,R) ---------------
__global__ __launch_bounds__(256) void xpose_kernel(
        const float* __restrict__ in, float* __restrict__ out, int R, int C) {
    __shared__ float tile[64][65];
    const int r0 = blockIdx.x * 64;
    const int c0 = blockIdx.y * 64;
    const int b  = blockIdx.z;
    const int tx = threadIdx.x & 63;
    const int ty = threadIdx.x >> 6;
    #pragma unroll
    for (int k = 0; k < 16; ++k) {
        const int r = ty * 16 + k;
        tile[r][tx] = in[((size_t)b * R + (r0 + r)) * C + c0 + tx];
    }
    __syncthreads();
    #pragma unroll
    for (int k = 0; k < 16; ++k) {
        const int r = ty * 16 + k;
        out[((size_t)b * C + (c0 + r)) * R + r0 + tx] = tile[tx][r];
    }
}

// -------- Kernel C: fused delta + chunked 3-phase selective scan -----------
// One block per (b,d). 16 groups x 16 n-lanes; group g owns t in [g*128,(g+1)*128).
// Phase 0: delta = softplus(dtpT . Wdt[d] + 2*bdt[d]) -> sdel (padded chunks);
//          stage x row -> sx.
// Phase 1: local scan (h0=0) -> per-chunk (P = exp(Aln*sum dl), q = end state).
// Phase 2: 16-step serial stitch (16 threads).
// Phase 3: re-scan with correct h0; y_t = sum_n C*h + x*D (10 shuffles / 4t);
//          y written into sdel (reuse).
// Epilogue: y *= silu(z) (z natively (b,d,l)); write yT coalesced. yT aliases xT.
__global__ __launch_bounds__(256) void scan_kernel(
        const float* __restrict__ xT, const float* __restrict__ z,
        const float* __restrict__ A_log, const float* __restrict__ Dp,
        const float* __restrict__ BcT, const float* __restrict__ CcT,
        const float* __restrict__ dtpT, const float* __restrict__ Wdt,
        const float* __restrict__ bdt, float* __restrict__ yT) {
    __shared__ float sdel[NCHUNK * CPAD];   // 8448 B; phase 3 reuses as y buffer
    __shared__ float sx[NCHUNK * CPAD];     // 8448 B
    __shared__ float sP[NCHUNK][NST], sq[NCHUNK][NST], scar[NCHUNK][NST];

    const int tid = threadIdx.x;
    const int ch = blockIdx.x;           // b*768 + d
    const int b = ch / DIM;
    const int d = ch % DIM;
    const size_t row = (size_t)ch * LSEQ;

    // ---- phase 0a: stage x row into padded chunks (conflict-free float4)
    {
        const float4* s2 = (const float4*)(xT + row);
        float4* d2 = (float4*)sx;
        #pragma unroll
        for (int i = 0; i < 2; ++i) {
            const int idx = tid + 256 * i;                 // float4 index 0..511
            d2[(idx >> 5) * CPAD4 + (idx & 31)] = s2[idx];
        }
    }
    // ---- phase 0b: fused delta into sdel
    {
        const float bb = 2.0f * bdt[d];
        const float* wd = Wdt + (size_t)d * RDT;           // uniform per block
        float w[RDT];
        #pragma unroll
        for (int k = 0; k < RDT; k += 4) {
            const float4 t = *(const float4*)(wd + k);
            w[k] = t.x; w[k+1] = t.y; w[k+2] = t.z; w[k+3] = t.w;
        }
        const float* dbase = dtpT + (size_t)b * RDT * LSEQ;
        #pragma unroll
        for (int i = 0; i < 2; ++i) {
            const int idx = tid + 256 * i;                 // float4 index over t
            float4 acc = make_float4(bb, bb, bb, bb);
            #pragma unroll
            for (int k = 0; k < RDT; ++k) {
                const float4 v = *(const float4*)(dbase + (size_t)k * LSEQ + idx * 4);
                acc.x = fmaf(v.x, w[k], acc.x);
                acc.y = fmaf(v.y, w[k], acc.y);
                acc.z = fmaf(v.z, w[k], acc.z);
                acc.w = fmaf(v.w, w[k], acc.w);
            }
            float4 sp;
            sp.x = (acc.x > 20.f) ? acc.x : log1pf(__expf(acc.x));
            sp.y = (acc.y > 20.f) ? acc.y : log1pf(__expf(acc.y));
            sp.z = (acc.z > 20.f) ? acc.z : log1pf(__expf(acc.z));
            sp.w = (acc.w > 20.f) ? acc.w : log1pf(__expf(acc.w));
            ((float4*)sdel)[(idx >> 5) * CPAD4 + (idx & 31)] = sp;
        }
    }
    __syncthreads();

    const int g = tid >> 4;
    const int n = tid & 15;
    const float Aln = -__expf(A_log[d * NST + n]);
    const float* Bbase = BcT + ((size_t)(b * NST + n)) * LSEQ + g * CLEN;
    const float* Cbase = CcT + ((size_t)(b * NST + n)) * LSEQ + g * CLEN;
    const float* dchunk = sdel + g * CPAD;
    const float* xchunk = sx + g * CPAD;

    // ---- phase 1: local scan, h0 = 0
    float h = 0.f, dsum = 0.f;
    for (int k = 0; k < CLEN; k += 4) {
        const float4 dl = *(const float4*)(dchunk + k);
        const float4 xv = *(const float4*)(xchunk + k);
        const float4 B4 = *(const float4*)(Bbase + k);
        dsum += (dl.x + dl.y) + (dl.z + dl.w);
        h = fmaf(__expf(dl.x * Aln), h, dl.x * xv.x * B4.x);
        h = fmaf(__expf(dl.y * Aln), h, dl.y * xv.y * B4.y);
        h = fmaf(__expf(dl.z * Aln), h, dl.z * xv.z * B4.z);
        h = fmaf(__expf(dl.w * Aln), h, dl.w * xv.w * B4.w);
    }
    sP[g][n] = __expf(Aln * dsum);   // product of all dA over the chunk
    sq[g][n] = h;
    __syncthreads();

    // ---- phase 2: serial stitch over 16 chunks
    if (tid < NST) {
        float car = 0.f;
        #pragma unroll
        for (int c = 0; c < NCHUNK; ++c) {
            scar[c][tid] = car;
            car = fmaf(sP[c][tid], car, sq[c][tid]);
        }
    }
    __syncthreads();

    // ---- phase 3: re-scan with correct h0; reduce y over n
    const float Dd = Dp[d];
    h = scar[g][n];
    float* ybuf = sdel;   // reuse: writes at [k..k+3] happen after the k-read
    for (int k = 0; k < CLEN; k += 4) {
        const float4 dl = *(const float4*)(dchunk + k);
        const float4 xv = *(const float4*)(xchunk + k);
        const float4 B4 = *(const float4*)(Bbase + k);
        const float4 C4 = *(const float4*)(Cbase + k);
        h = fmaf(__expf(dl.x * Aln), h, dl.x * xv.x * B4.x); float p0 = h * C4.x;
        h = fmaf(__expf(dl.y * Aln), h, dl.y * xv.y * B4.y); float p1 = h * C4.y;
        h = fmaf(__expf(dl.z * Aln), h, dl.z * xv.z * B4.z); float p2 = h * C4.z;
        h = fmaf(__expf(dl.w * Aln), h, dl.w * xv.w * B4.w); float p3 = h * C4.w;
        // 2-stage butterfly on each partial (quad sums), select by n&3, 2 more stages
        p0 += __shfl_xor(p0, 1); p0 += __shfl_xor(p0, 2);
        p1 += __shfl_xor(p1, 1); p1 += __shfl_xor(p1, 2);
        p2 += __shfl_xor(p2, 1); p2 += __shfl_xor(p2, 2);
        p3 += __shfl_xor(p3, 1); p3 += __shfl_xor(p3, 2);
        float v = (n & 1) ? ((n & 2) ? p3 : p1) : ((n & 2) ? p2 : p0);
        v += __shfl_xor(v, 4);
        v += __shfl_xor(v, 8);
        if (n < 4) {   // lane n holds total for t = k+n
            const float xvn = (n == 0) ? xv.x : (n == 1) ? xv.y : (n == 2) ? xv.z : xv.w;
            ybuf[g * CPAD + k + n] = fmaf(xvn, Dd, v);
        }
    }
    __syncthreads();

    // ---- epilogue: y *= silu(z), write yT (coalesced; yT aliases xT — x is in LDS)
    const float* zrow = z + row;
    float* yrow = yT + row;
    for (int i = tid; i < LSEQ; i += 256) {
        const float zv = zrow[i];
        const float sig = 1.0f / (1.0f + __expf(-zv));
        yrow[i] = ybuf[(i >> 7) * CPAD + (i & 127)] * zv * sig;
    }
}

extern "C" void kernel_launch(void* const* d_in, const int* in_sizes, int n_in,
                              void* d_out, int out_size, void* d_ws, size_t ws_size,
                              hipStream_t stream) {
    const float* x     = (const float*)d_in[0];  // (2,2048,768)
    const float* z     = (const float*)d_in[1];  // (2,768,2048)
    const float* A_log = (const float*)d_in[2];  // (768,16)
    const float* D     = (const float*)d_in[3];  // (768,)
    const float* Wx    = (const float*)d_in[4];  // (1680,768)
    const float* Wdt   = (const float*)d_in[5];  // (768,48)
    const float* bdt   = (const float*)d_in[6];  // (768,)
    float* out = (float*)d_out;

    // ws layout (floats):
    //   BcT  [2*16*2048]  =  65536
    //   CcT  [2*16*2048]  =  65536
    //   dtpT [2*48*2048]  = 196608
    //   xT   [2*768*2048] = 3145728   (scan writes yT over it after staging x in LDS)
    float* ws   = (float*)d_ws;
    float* BcT  = ws;
    float* CcT  = BcT + (size_t)BATCH * NST * LSEQ;
    float* dtpT = CcT + (size_t)BATCH * NST * LSEQ;
    float* xT   = dtpT + (size_t)BATCH * RDT * LSEQ;
    float* yT   = xT;   // alias: each block consumes its x row into LDS before writing y

    hipLaunchKernelGGL(proj_kernel, dim3(BL / 16), dim3(256), 0, stream,
                       x, Wx, BcT, CcT, dtpT);
    hipLaunchKernelGGL(xpose_kernel, dim3(LSEQ / 64, DIM / 64, BATCH), dim3(256), 0, stream,
                       x, xT, LSEQ, DIM);
    hipLaunchKernelGGL(scan_kernel, dim3(BATCH * DIM), dim3(256), 0, stream,
                       xT, z, A_log, D, BcT, CcT, dtpT, Wdt, bdt, yT);
    hipLaunchKernelGGL(xpose_kernel, dim3(DIM / 64, LSEQ / 64, BATCH), dim3(256), 0, stream,
                       yT, out, DIM, LSEQ);
}

// Round 4
// 286.100 us; speedup vs baseline: 4.4384x; 1.1098x over previous
//
#include <hip/hip_runtime.h>
#include <math.h>

// Problem constants (S4Checkpointed): b=2, L=2048, d=768, n=16, r=48
#define BATCH 2
#define LSEQ  2048
#define DIM   768
#define NST   16
#define RDT   48
#define BL    (BATCH*LSEQ)   // 4096
#define NCHUNK 32
#define CLEN   (LSEQ/NCHUNK) // 64
#define CPAD   68            // chunk stride floats: 68%32==4 -> wave's 4 groups on distinct banks
#define NPACK  (CLEN/4)      // 16 float4 packs per chunk

// -------- Kernel A: sliced projection --------------------------------------
// Only rows 0..15 (B), 32..47 (C), 1584..1631 (dt) of W_xproj are used.
// Grid (BL/16, 4): j-range split 4x for occupancy. Wave computes 5 j's.
__global__ __launch_bounds__(256) void proj_kernel(
        const float* __restrict__ x, const float* __restrict__ Wx,
        float* __restrict__ BcT, float* __restrict__ CcT, float* __restrict__ dtpT) {
    __shared__ float xs[16 * DIM];   // 48 KB
    const int bl0 = blockIdx.x * 16;
    const int tid = threadIdx.x;
    const float* xsrc = x + (size_t)bl0 * DIM;
    for (int i = tid; i < 16 * DIM / 4; i += 256)
        ((float4*)xs)[i] = ((const float4*)xsrc)[i];
    __syncthreads();

    const int wave = tid >> 6;
    const int lane = tid & 63;
    for (int jj = 0; jj < 5; ++jj) {
        const int j = blockIdx.y * 20 + wave * 5 + jj;   // 0..79
        const int row = (j < 16) ? j : ((j < 32) ? (j + 16) : (j + 1552));
        const float* wrow = Wx + (size_t)row * DIM;
        float w[12];
        #pragma unroll
        for (int i = 0; i < 12; ++i) w[i] = wrow[lane + i * 64];
        for (int l = 0; l < 16; ++l) {
            float s = 0.f;
            #pragma unroll
            for (int i = 0; i < 12; ++i) s += w[i] * xs[l * DIM + lane + i * 64];
            #pragma unroll
            for (int m = 32; m >= 1; m >>= 1) s += __shfl_xor(s, m, 64);
            if (lane == 0) {
                const int bl = bl0 + l;
                const int b = bl >> 11;       // /2048
                const int ll = bl & 2047;
                if (j < 16)       BcT[((size_t)(b * NST + j)) * LSEQ + ll]         = s;
                else if (j < 32)  CcT[((size_t)(b * NST + (j - 16))) * LSEQ + ll]  = s;
                else              dtpT[((size_t)(b * RDT + (j - 32))) * LSEQ + ll] = s;
            }
        }
    }
}

// -------- Kernel T: 64x64 tiled transpose (b,R,C) -> (b,C,R) ---------------
__global__ __launch_bounds__(256) void xpose_kernel(
        const float* __restrict__ in, float* __restrict__ out, int R, int C) {
    __shared__ float tile[64][65];
    const int r0 = blockIdx.x * 64;
    const int c0 = blockIdx.y * 64;
    const int b  = blockIdx.z;
    const int tx = threadIdx.x & 63;
    const int ty = threadIdx.x >> 6;
    #pragma unroll
    for (int k = 0; k < 16; ++k) {
        const int r = ty * 16 + k;
        tile[r][tx] = in[((size_t)b * R + (r0 + r)) * C + c0 + tx];
    }
    __syncthreads();
    #pragma unroll
    for (int k = 0; k < 16; ++k) {
        const int r = ty * 16 + k;
        out[((size_t)b * C + (c0 + r)) * R + r0 + tx] = tile[tx][r];
    }
}

// -------- Kernel C: fused delta + chunked scan (pack-trick, Kogge-Stone) ----
// One block (512 thr) per (b,d). 32 groups x 16 n-lanes; group g owns 64 t.
// Phase 0: stage x; delta = softplus(dtpT . Wdt[d] + 2*bdt[d]) -> sdel.
// Phase 1: per-pack cumulative-delta trick -> chain = 1 fma / 4t; emit (P,q).
// Phase 2: Kogge-Stone scan of (P,q) transforms over 32 chunks (5 steps).
// Phase 3: re-scan with carry h0; h_i = fma(E_i, h0, s_i) (independent);
//          y = sum_n C*h + x*D; write into sdel.
// Epilogue: y *= silu(z); write yT (aliases xT).
__global__ __launch_bounds__(512) void scan_kernel(
        const float* __restrict__ xT, const float* __restrict__ z,
        const float* __restrict__ A_log, const float* __restrict__ Dp,
        const float* __restrict__ BcT, const float* __restrict__ CcT,
        const float* __restrict__ dtpT, const float* __restrict__ Wdt,
        const float* __restrict__ bdt, float* __restrict__ yT) {
    __shared__ float sdel[NCHUNK * CPAD];   // 8704 B; phase 3 reuses as y buffer
    __shared__ float sx[NCHUNK * CPAD];     // 8704 B
    __shared__ float sP[NCHUNK][NST];       // 2 KB
    __shared__ float sq[NCHUNK][NST];       // 2 KB
    __shared__ float sw[RDT];

    const int tid = threadIdx.x;
    const int ch = blockIdx.x;           // b*768 + d
    const int b = ch / DIM;
    const int d = ch % DIM;
    const size_t row = (size_t)ch * LSEQ;

    // ---- phase 0a: stage x row (padded chunks) + Wdt row to LDS
    if (tid < RDT) sw[tid] = Wdt[(size_t)d * RDT + tid];
    {
        const float4 xv4 = ((const float4*)(xT + row))[tid];
        ((float4*)sx)[(tid >> 4) * (CPAD / 4) + (tid & 15)] = xv4;
    }
    __syncthreads();

    // ---- phase 0b: fused delta -> sdel. Thread owns float4 t-column tid.
    {
        const float bb = 2.0f * bdt[d];
        const float* dbase = dtpT + (size_t)b * RDT * LSEQ;
        float4 acc = make_float4(bb, bb, bb, bb);
        #pragma unroll 3
        for (int k4 = 0; k4 < RDT / 4; ++k4) {
            const float4 wv = ((const float4*)sw)[k4];
            #pragma unroll
            for (int j = 0; j < 4; ++j) {
                const int k = k4 * 4 + j;
                const float wk = (j == 0) ? wv.x : (j == 1) ? wv.y : (j == 2) ? wv.z : wv.w;
                const float4 v = ((const float4*)(dbase + (size_t)k * LSEQ))[tid];
                acc.x = fmaf(v.x, wk, acc.x);
                acc.y = fmaf(v.y, wk, acc.y);
                acc.z = fmaf(v.z, wk, acc.z);
                acc.w = fmaf(v.w, wk, acc.w);
            }
        }
        float4 sp;
        sp.x = (acc.x > 20.f) ? acc.x : __logf(1.f + __expf(acc.x));
        sp.y = (acc.y > 20.f) ? acc.y : __logf(1.f + __expf(acc.y));
        sp.z = (acc.z > 20.f) ? acc.z : __logf(1.f + __expf(acc.z));
        sp.w = (acc.w > 20.f) ? acc.w : __logf(1.f + __expf(acc.w));
        ((float4*)sdel)[(tid >> 4) * (CPAD / 4) + (tid & 15)] = sp;
    }
    __syncthreads();

    const int g = tid >> 4;          // chunk 0..31
    const int n = tid & 15;          // state index
    const float Aln = -__expf(A_log[d * NST + n]);
    const float* Bg = BcT + ((size_t)(b * NST + n)) * LSEQ + g * CLEN;
    const float* Cg = CcT + ((size_t)(b * NST + n)) * LSEQ + g * CLEN;
    const float* dchunk = sdel + g * CPAD;
    const float* xchunk = sx + g * CPAD;

    // ---- phase 1: local scan with pack trick (chain: 1 fma + 1 add per 4t)
    {
        float h = 0.f, cumtot = 0.f;
        float4 Bn_ = ((const float4*)Bg)[0];
        #pragma unroll 4
        for (int p = 0; p < NPACK; ++p) {
            const float4 B4 = Bn_;
            if (p < NPACK - 1) Bn_ = ((const float4*)Bg)[p + 1];
            const float4 dl = *(const float4*)(dchunk + 4 * p);
            const float4 xv = *(const float4*)(xchunk + 4 * p);
            const float u0 = dl.x * xv.x * B4.x, u1 = dl.y * xv.y * B4.y;
            const float u2 = dl.z * xv.z * B4.z, u3 = dl.w * xv.w * B4.w;
            const float c3 = (dl.x + dl.y) + (dl.z + dl.w);
            const float dA1 = __expf(Aln * dl.y), dA2 = __expf(Aln * dl.z), dA3 = __expf(Aln * dl.w);
            float s = u0;
            s = fmaf(dA1, s, u1); s = fmaf(dA2, s, u2); s = fmaf(dA3, s, u3);
            const float E3 = __expf(Aln * c3);
            h = fmaf(E3, h, s);          // the only cross-pack chain op
            cumtot += c3;
        }
        sP[g][n] = __expf(Aln * cumtot);
        sq[g][n] = h;
    }
    __syncthreads();

    // ---- phase 2: Kogge-Stone inclusive scan of transforms over chunks
    {
        float Pc = sP[g][n], qc = sq[g][n];
        #pragma unroll
        for (int s = 1; s < NCHUNK; s <<= 1) {
            float Pp = 1.f, qp = 0.f;
            if (g >= s) { Pp = sP[g - s][n]; qp = sq[g - s][n]; }
            __syncthreads();
            qc = fmaf(Pc, qp, qc);
            Pc *= Pp;
            sP[g][n] = Pc; sq[g][n] = qc;
            __syncthreads();
        }
    }

    // ---- phase 3: re-scan with carry; h_i independent given pack entry h
    {
        float h = (g == 0) ? 0.f : sq[g - 1][n];
        const float Dd = Dp[d];
        float* ybuf = sdel;              // reuse: pack p written after pack p read
        float4 Bn_ = ((const float4*)Bg)[0];
        float4 Cn_ = ((const float4*)Cg)[0];
        #pragma unroll 4
        for (int p = 0; p < NPACK; ++p) {
            const float4 B4 = Bn_, C4 = Cn_;
            if (p < NPACK - 1) { Bn_ = ((const float4*)Bg)[p + 1]; Cn_ = ((const float4*)Cg)[p + 1]; }
            const float4 dl = *(const float4*)(dchunk + 4 * p);
            const float4 xv = *(const float4*)(xchunk + 4 * p);
            const float u0 = dl.x * xv.x * B4.x, u1 = dl.y * xv.y * B4.y;
            const float u2 = dl.z * xv.z * B4.z, u3 = dl.w * xv.w * B4.w;
            const float c1 = dl.x + dl.y, c2 = c1 + dl.z, c3 = c2 + dl.w;
            const float dA1 = __expf(Aln * dl.y), dA2 = __expf(Aln * dl.z), dA3 = __expf(Aln * dl.w);
            const float E0 = __expf(Aln * dl.x), E1 = __expf(Aln * c1);
            const float E2 = __expf(Aln * c2),  E3 = __expf(Aln * c3);
            const float s0 = u0;
            const float s1 = fmaf(dA1, s0, u1);
            const float s2 = fmaf(dA2, s1, u2);
            const float s3 = fmaf(dA3, s2, u3);
            const float h0 = fmaf(E0, h, s0);
            const float h1 = fmaf(E1, h, s1);
            const float h2 = fmaf(E2, h, s2);
            const float h3 = fmaf(E3, h, s3);
            h = h3;                      // 1-fma cross-pack chain
            float p0 = h0 * C4.x, p1 = h1 * C4.y, p2 = h2 * C4.z, p3 = h3 * C4.w;
            p0 += __shfl_xor(p0, 1); p0 += __shfl_xor(p0, 2);
            p1 += __shfl_xor(p1, 1); p1 += __shfl_xor(p1, 2);
            p2 += __shfl_xor(p2, 1); p2 += __shfl_xor(p2, 2);
            p3 += __shfl_xor(p3, 1); p3 += __shfl_xor(p3, 2);
            float v = (n & 1) ? ((n & 2) ? p3 : p1) : ((n & 2) ? p2 : p0);
            v += __shfl_xor(v, 4);
            v += __shfl_xor(v, 8);
            if (n < 4) {                 // lane n holds total for t = 4p+n
                const float xvn = (n == 0) ? xv.x : (n == 1) ? xv.y : (n == 2) ? xv.z : xv.w;
                ybuf[g * CPAD + 4 * p + n] = fmaf(xvn, Dd, v);
            }
        }
    }
    __syncthreads();

    // ---- epilogue: y *= silu(z), write yT (aliases xT; x already consumed)
    {
        const float* zrow = z + row;
        float* yrow = yT + row;
        #pragma unroll
        for (int i = tid; i < LSEQ; i += 512) {
            const float zv = zrow[i];
            const float sig = 1.0f / (1.0f + __expf(-zv));
            yrow[i] = sdel[(i >> 6) * CPAD + (i & 63)] * zv * sig;
        }
    }
}

extern "C" void kernel_launch(void* const* d_in, const int* in_sizes, int n_in,
                              void* d_out, int out_size, void* d_ws, size_t ws_size,
                              hipStream_t stream) {
    const float* x     = (const float*)d_in[0];  // (2,2048,768)
    const float* z     = (const float*)d_in[1];  // (2,768,2048)
    const float* A_log = (const float*)d_in[2];  // (768,16)
    const float* D     = (const float*)d_in[3];  // (768,)
    const float* Wx    = (const float*)d_in[4];  // (1680,768)
    const float* Wdt   = (const float*)d_in[5];  // (768,48)
    const float* bdt   = (const float*)d_in[6];  // (768,)
    float* out = (float*)d_out;

    // ws layout (floats): BcT[2*16*2048] | CcT[2*16*2048] | dtpT[2*48*2048] | xT[2*768*2048]
    float* ws   = (float*)d_ws;
    float* BcT  = ws;
    float* CcT  = BcT + (size_t)BATCH * NST * LSEQ;
    float* dtpT = CcT + (size_t)BATCH * NST * LSEQ;
    float* xT   = dtpT + (size_t)BATCH * RDT * LSEQ;
    float* yT   = xT;   // alias: each block consumes its x row into LDS before writing y

    hipLaunchKernelGGL(proj_kernel, dim3(BL / 16, 4), dim3(256), 0, stream,
                       x, Wx, BcT, CcT, dtpT);
    hipLaunchKernelGGL(xpose_kernel, dim3(LSEQ / 64, DIM / 64, BATCH), dim3(256), 0, stream,
                       x, xT, LSEQ, DIM);
    hipLaunchKernelGGL(scan_kernel, dim3(BATCH * DIM), dim3(512), 0, stream,
                       xT, z, A_log, D, BcT, CcT, dtpT, Wdt, bdt, yT);
    hipLaunchKernelGGL(xpose_kernel, dim3(DIM / 64, LSEQ / 64, BATCH), dim3(256), 0, stream,
                       yT, out, DIM, LSEQ);
}

// Round 5
// 198.599 us; speedup vs baseline: 6.3939x; 1.4406x over previous
//
#include <hip/hip_runtime.h>
#include <math.h>

// Problem constants (S4Checkpointed): b=2, L=2048, d=768, n=16, r=48
#define BATCH 2
#define LSEQ  2048
#define DIM   768
#define NST   16
#define RDT   48
#define BL    (BATCH*LSEQ)   // 4096
#define NCHUNK 32
#define CLEN   (LSEQ/NCHUNK) // 64
#define CPAD   68            // chunk stride floats: 68%32==4 -> wave's 4 groups on distinct banks
#define NPACK  (CLEN/4)      // 16 float4 packs per chunk
#define LP4    (LSEQ/4)      // 512 t-packs per (b)

// -------- Kernel A: sliced projection --------------------------------------
// Only rows 0..15 (B), 32..47 (C), 1584..1631 (dt) of W_xproj are used.
// B/C written in pack-transposed layout: float4[b][t/4][n], component j = t%4,
// so the scan's per-pack loads are coalesced (16 consecutive float4 per group).
// dt written transposed as (b, r, L).
__global__ __launch_bounds__(256) void proj_kernel(
        const float* __restrict__ x, const float* __restrict__ Wx,
        float* __restrict__ Bpk, float* __restrict__ Cpk, float* __restrict__ dtpT) {
    __shared__ float xs[16 * DIM];   // 48 KB
    const int bl0 = blockIdx.x * 16;
    const int tid = threadIdx.x;
    const float* xsrc = x + (size_t)bl0 * DIM;
    for (int i = tid; i < 16 * DIM / 4; i += 256)
        ((float4*)xs)[i] = ((const float4*)xsrc)[i];
    __syncthreads();

    const int wave = tid >> 6;
    const int lane = tid & 63;
    for (int jj = 0; jj < 5; ++jj) {
        const int j = blockIdx.y * 20 + wave * 5 + jj;   // 0..79
        const int row = (j < 16) ? j : ((j < 32) ? (j + 16) : (j + 1552));
        const float* wrow = Wx + (size_t)row * DIM;
        float w[12];
        #pragma unroll
        for (int i = 0; i < 12; ++i) w[i] = wrow[lane + i * 64];
        for (int l = 0; l < 16; ++l) {
            float s = 0.f;
            #pragma unroll
            for (int i = 0; i < 12; ++i) s += w[i] * xs[l * DIM + lane + i * 64];
            #pragma unroll
            for (int m = 32; m >= 1; m >>= 1) s += __shfl_xor(s, m, 64);
            if (lane == 0) {
                const int bl = bl0 + l;
                const int b  = bl >> 11;       // /2048
                const int t  = bl & 2047;
                const size_t pkidx = ((((size_t)(b * LP4 + (t >> 2)) * NST + ((j < 32) ? (j & 15) : 0)) << 2) | (t & 3));
                if (j < 16)       Bpk[pkidx] = s;
                else if (j < 32)  Cpk[pkidx] = s;
                else              dtpT[((size_t)(b * RDT + (j - 32))) * LSEQ + t] = s;
            }
        }
    }
}

// -------- Kernel T: 64x64 tiled transpose (b,R,C) -> (b,C,R) ---------------
__global__ __launch_bounds__(256) void xpose_kernel(
        const float* __restrict__ in, float* __restrict__ out, int R, int C) {
    __shared__ float tile[64][65];
    const int r0 = blockIdx.x * 64;
    const int c0 = blockIdx.y * 64;
    const int b  = blockIdx.z;
    const int tx = threadIdx.x & 63;
    const int ty = threadIdx.x >> 6;
    #pragma unroll
    for (int k = 0; k < 16; ++k) {
        const int r = ty * 16 + k;
        tile[r][tx] = in[((size_t)b * R + (r0 + r)) * C + c0 + tx];
    }
    __syncthreads();
    #pragma unroll
    for (int k = 0; k < 16; ++k) {
        const int r = ty * 16 + k;
        out[((size_t)b * C + (c0 + r)) * R + r0 + tx] = tile[tx][r];
    }
}

// -------- Kernel C: fused delta + chunked scan (pack-trick, Kogge-Stone) ----
// One block (512 thr) per (b,d). 32 groups x 16 n-lanes; group g owns 64 t.
// B/C loads use the pack-transposed layout -> coalesced (4x256B segments/instr).
__global__ __launch_bounds__(512) void scan_kernel(
        const float* __restrict__ xT, const float* __restrict__ z,
        const float* __restrict__ A_log, const float* __restrict__ Dp,
        const float* __restrict__ Bpk, const float* __restrict__ Cpk,
        const float* __restrict__ dtpT, const float* __restrict__ Wdt,
        const float* __restrict__ bdt, float* __restrict__ yT) {
    __shared__ float sdel[NCHUNK * CPAD];   // 8704 B; phase 3 reuses as y buffer
    __shared__ float sx[NCHUNK * CPAD];     // 8704 B
    __shared__ float sP[NCHUNK][NST];       // 2 KB
    __shared__ float sq[NCHUNK][NST];       // 2 KB
    __shared__ float sw[RDT];

    const int tid = threadIdx.x;
    const int ch = blockIdx.x;           // b*768 + d
    const int b = ch / DIM;
    const int d = ch % DIM;
    const size_t row = (size_t)ch * LSEQ;

    // ---- phase 0a: stage x row (padded chunks) + Wdt row to LDS
    if (tid < RDT) sw[tid] = Wdt[(size_t)d * RDT + tid];
    {
        const float4 xv4 = ((const float4*)(xT + row))[tid];
        ((float4*)sx)[(tid >> 4) * (CPAD / 4) + (tid & 15)] = xv4;
    }
    __syncthreads();

    // ---- phase 0b: fused delta -> sdel. Thread owns float4 t-column tid.
    {
        const float bb = 2.0f * bdt[d];
        const float* dbase = dtpT + (size_t)b * RDT * LSEQ;
        float4 acc = make_float4(bb, bb, bb, bb);
        #pragma unroll 3
        for (int k4 = 0; k4 < RDT / 4; ++k4) {
            const float4 wv = ((const float4*)sw)[k4];
            #pragma unroll
            for (int j = 0; j < 4; ++j) {
                const int k = k4 * 4 + j;
                const float wk = (j == 0) ? wv.x : (j == 1) ? wv.y : (j == 2) ? wv.z : wv.w;
                const float4 v = ((const float4*)(dbase + (size_t)k * LSEQ))[tid];
                acc.x = fmaf(v.x, wk, acc.x);
                acc.y = fmaf(v.y, wk, acc.y);
                acc.z = fmaf(v.z, wk, acc.z);
                acc.w = fmaf(v.w, wk, acc.w);
            }
        }
        float4 sp;
        sp.x = (acc.x > 20.f) ? acc.x : __logf(1.f + __expf(acc.x));
        sp.y = (acc.y > 20.f) ? acc.y : __logf(1.f + __expf(acc.y));
        sp.z = (acc.z > 20.f) ? acc.z : __logf(1.f + __expf(acc.z));
        sp.w = (acc.w > 20.f) ? acc.w : __logf(1.f + __expf(acc.w));
        ((float4*)sdel)[(tid >> 4) * (CPAD / 4) + (tid & 15)] = sp;
    }
    __syncthreads();

    const int g = tid >> 4;          // chunk 0..31
    const int n = tid & 15;          // state index
    const float Aln = -__expf(A_log[d * NST + n]);
    // pack-transposed base: float4 index (b*512 + g*16 + p)*16 + n
    const float4* Bg = (const float4*)Bpk + ((size_t)(b * LP4 + g * NPACK) * NST + n);
    const float4* Cg = (const float4*)Cpk + ((size_t)(b * LP4 + g * NPACK) * NST + n);
    const float* dchunk = sdel + g * CPAD;
    const float* xchunk = sx + g * CPAD;

    // ---- phase 1: local scan with pack trick (chain: 1 fma per 4t)
    {
        float h = 0.f, Ptot = 1.f;
        float4 Bn_ = Bg[0];
        #pragma unroll 4
        for (int p = 0; p < NPACK; ++p) {
            const float4 B4 = Bn_;
            if (p < NPACK - 1) Bn_ = Bg[(p + 1) * NST];
            const float4 dl = *(const float4*)(dchunk + 4 * p);
            const float4 xv = *(const float4*)(xchunk + 4 * p);
            const float u0 = dl.x * xv.x * B4.x, u1 = dl.y * xv.y * B4.y;
            const float u2 = dl.z * xv.z * B4.z, u3 = dl.w * xv.w * B4.w;
            const float e0  = __expf(Aln * dl.x), dA1 = __expf(Aln * dl.y);
            const float dA2 = __expf(Aln * dl.z), dA3 = __expf(Aln * dl.w);
            float s = u0;
            s = fmaf(dA1, s, u1); s = fmaf(dA2, s, u2); s = fmaf(dA3, s, u3);
            const float E3 = ((e0 * dA1) * (dA2 * dA3));
            h = fmaf(E3, h, s);          // the only cross-pack chain op
            Ptot *= E3;
        }
        sP[g][n] = Ptot;
        sq[g][n] = h;
    }
    __syncthreads();

    // ---- phase 2: Kogge-Stone inclusive scan of transforms over chunks
    {
        float Pc = sP[g][n], qc = sq[g][n];
        #pragma unroll
        for (int s = 1; s < NCHUNK; s <<= 1) {
            float Pp = 1.f, qp = 0.f;
            if (g >= s) { Pp = sP[g - s][n]; qp = sq[g - s][n]; }
            __syncthreads();
            qc = fmaf(Pc, qp, qc);
            Pc *= Pp;
            sP[g][n] = Pc; sq[g][n] = qc;
            __syncthreads();
        }
    }

    // ---- phase 3: re-scan with carry; h_i independent given pack entry h
    {
        float h = (g == 0) ? 0.f : sq[g - 1][n];
        const float Dd = Dp[d];
        float* ybuf = sdel;              // reuse: pack p written after pack p read
        float4 Bn_ = Bg[0];
        float4 Cn_ = Cg[0];
        #pragma unroll 4
        for (int p = 0; p < NPACK; ++p) {
            const float4 B4 = Bn_, C4 = Cn_;
            if (p < NPACK - 1) { Bn_ = Bg[(p + 1) * NST]; Cn_ = Cg[(p + 1) * NST]; }
            const float4 dl = *(const float4*)(dchunk + 4 * p);
            const float4 xv = *(const float4*)(xchunk + 4 * p);
            const float u0 = dl.x * xv.x * B4.x, u1 = dl.y * xv.y * B4.y;
            const float u2 = dl.z * xv.z * B4.z, u3 = dl.w * xv.w * B4.w;
            const float E0  = __expf(Aln * dl.x), dA1 = __expf(Aln * dl.y);
            const float dA2 = __expf(Aln * dl.z), dA3 = __expf(Aln * dl.w);
            const float E1 = E0 * dA1, E2 = E1 * dA2, E3 = E2 * dA3;
            const float s0 = u0;
            const float s1 = fmaf(dA1, s0, u1);
            const float s2 = fmaf(dA2, s1, u2);
            const float s3 = fmaf(dA3, s2, u3);
            const float h0 = fmaf(E0, h, s0);
            const float h1 = fmaf(E1, h, s1);
            const float h2 = fmaf(E2, h, s2);
            const float h3 = fmaf(E3, h, s3);
            h = h3;                      // 1-fma cross-pack chain
            float p0 = h0 * C4.x, p1 = h1 * C4.y, p2 = h2 * C4.z, p3 = h3 * C4.w;
            p0 += __shfl_xor(p0, 1); p0 += __shfl_xor(p0, 2);
            p1 += __shfl_xor(p1, 1); p1 += __shfl_xor(p1, 2);
            p2 += __shfl_xor(p2, 1); p2 += __shfl_xor(p2, 2);
            p3 += __shfl_xor(p3, 1); p3 += __shfl_xor(p3, 2);
            float v = (n & 1) ? ((n & 2) ? p3 : p1) : ((n & 2) ? p2 : p0);
            v += __shfl_xor(v, 4);
            v += __shfl_xor(v, 8);
            if (n < 4) {                 // lane n holds total for t = 4p+n
                const float xvn = (n == 0) ? xv.x : (n == 1) ? xv.y : (n == 2) ? xv.z : xv.w;
                ybuf[g * CPAD + 4 * p + n] = fmaf(xvn, Dd, v);
            }
        }
    }
    __syncthreads();

    // ---- epilogue: y *= silu(z), write yT (aliases xT; x already consumed)
    {
        const float* zrow = z + row;
        float* yrow = yT + row;
        #pragma unroll
        for (int i = tid; i < LSEQ; i += 512) {
            const float zv = zrow[i];
            const float sig = 1.0f / (1.0f + __expf(-zv));
            yrow[i] = sdel[(i >> 6) * CPAD + (i & 63)] * zv * sig;
        }
    }
}

extern "C" void kernel_launch(void* const* d_in, const int* in_sizes, int n_in,
                              void* d_out, int out_size, void* d_ws, size_t ws_size,
                              hipStream_t stream) {
    const float* x     = (const float*)d_in[0];  // (2,2048,768)
    const float* z     = (const float*)d_in[1];  // (2,768,2048)
    const float* A_log = (const float*)d_in[2];  // (768,16)
    const float* D     = (const float*)d_in[3];  // (768,)
    const float* Wx    = (const float*)d_in[4];  // (1680,768)
    const float* Wdt   = (const float*)d_in[5];  // (768,48)
    const float* bdt   = (const float*)d_in[6];  // (768,)
    float* out = (float*)d_out;

    // ws layout (floats): Bpk[2*512*16*4] | Cpk[2*512*16*4] | dtpT[2*48*2048] | xT[2*768*2048]
    float* ws   = (float*)d_ws;
    float* Bpk  = ws;
    float* Cpk  = Bpk + (size_t)BATCH * LP4 * NST * 4;
    float* dtpT = Cpk + (size_t)BATCH * LP4 * NST * 4;
    float* xT   = dtpT + (size_t)BATCH * RDT * LSEQ;
    float* yT   = xT;   // alias: each block consumes its x row into LDS before writing y

    hipLaunchKernelGGL(proj_kernel, dim3(BL / 16, 4), dim3(256), 0, stream,
                       x, Wx, Bpk, Cpk, dtpT);
    hipLaunchKernelGGL(xpose_kernel, dim3(LSEQ / 64, DIM / 64, BATCH), dim3(256), 0, stream,
                       x, xT, LSEQ, DIM);
    hipLaunchKernelGGL(scan_kernel, dim3(BATCH * DIM), dim3(512), 0, stream,
                       xT, z, A_log, D, Bpk, Cpk, dtpT, Wdt, bdt, yT);
    hipLaunchKernelGGL(xpose_kernel, dim3(DIM / 64, LSEQ / 64, BATCH), dim3(256), 0, stream,
                       yT, out, DIM, LSEQ);
}